// Round 9
// baseline (288.130 us; speedup 1.0000x reference)
//
#include <hip/hip_runtime.h>
#include <cstdint>
#include <cstddef>

// ---------------------------------------------------------------
// SparseAttention: B=2 L=4096 D=1024 H=16 HD=64 BS=64 NB=64 MAXB=11
// ---------------------------------------------------------------

#define MAXB 11
#define NT   16    // K-tiles: K=1024 / BK=64

typedef __attribute__((ext_vector_type(8))) short short8;
typedef __attribute__((ext_vector_type(4))) float f32x4;

#define MFMA16(a, b, c) __builtin_amdgcn_mfma_f32_16x16x32_bf16((a), (b), (c), 0, 0, 0)

#define QSCALE 0.18033688011112042f   // 0.125 * log2(e)
#define LOG2E  1.44269504089f

#define BAR()   asm volatile("s_barrier" ::: "memory")
#define LGKM0() asm volatile("s_waitcnt lgkmcnt(0)" ::: "memory")
#define SCHED0() __builtin_amdgcn_sched_barrier(0)
#define VMC4()  asm volatile("s_waitcnt vmcnt(4)" ::: "memory")
#define VMC0()  asm volatile("s_waitcnt vmcnt(0)" ::: "memory")

__device__ __forceinline__ ushort f2bf(float f) {
  uint32_t u = __float_as_uint(f);
  u += 0x7FFFu + ((u >> 16) & 1u);   // RNE
  return (ushort)(u >> 16);
}

__device__ __forceinline__ uint32_t cvt_pk_bf16(float lo, float hi) {
  uint32_t r;
  asm("v_cvt_pk_bf16_f32 %0, %1, %2" : "=v"(r) : "v"(lo), "v"(hi));
  return r;
}

__device__ __forceinline__ void gload_lds16(const ushort* g, ushort* l) {
  __builtin_amdgcn_global_load_lds((const __attribute__((address_space(1))) void*)g,
                                   (__attribute__((address_space(3))) void*)l, 16, 0, 0);
}

// ---------------- f32 -> bf16 conversion ----------------
__global__ __launch_bounds__(256) void cvt_kernel(const float* __restrict__ src,
                                                  ushort* __restrict__ dst, int n4) {
  int i = blockIdx.x * 256 + threadIdx.x;
  if (i >= n4) return;
  const float4 v = reinterpret_cast<const float4*>(src)[i];
  ushort4 o;
  o.x = f2bf(v.x); o.y = f2bf(v.y); o.z = f2bf(v.z); o.w = f2bf(v.w);
  reinterpret_cast<ushort4*>(dst)[i] = o;
}

// fused weight conversion: Wq,Wk,Wv -> Wqkv (contig), Wo -> Wob
__global__ __launch_bounds__(256) void cvt4_kernel(const float* __restrict__ wq,
                                                   const float* __restrict__ wk,
                                                   const float* __restrict__ wv,
                                                   const float* __restrict__ wo,
                                                   ushort* __restrict__ wqkv,
                                                   ushort* __restrict__ wob) {
  int i = blockIdx.x * 256 + threadIdx.x;      // 0 .. 4*262144-1
  const int part = i >> 18;
  const int j = i & 262143;
  const float* src = (part == 0) ? wq : (part == 1) ? wk : (part == 2) ? wv : wo;
  const float4 v = reinterpret_cast<const float4*>(src)[j];
  ushort4 o;
  o.x = f2bf(v.x); o.y = f2bf(v.y); o.z = f2bf(v.z); o.w = f2bf(v.w);
  if (part < 3) reinterpret_cast<ushort4*>(wqkv)[part * 262144 + j] = o;
  else          reinterpret_cast<ushort4*>(wob)[j] = o;
}

// ---------------- phase-pipelined GEMM mainloop (round-3 structure, measured 65.6us) ----------------
// BM=256, BN=128, BK=64, 512 threads = 8 waves (2M x 4N), wave tile 128x32.
#define AB_(buf,h) ((buf)*16384 + (h)*8192)         // A base, elems
#define BB_(buf,h) (32768 + (buf)*8192 + (h)*4096)  // B base, elems

__device__ __forceinline__ void gemm8_mainloop(const ushort* __restrict__ Ag,
                                               const ushort* __restrict__ Bg,
                                               int m0, int n0,
                                               ushort* smem, f32x4 acc[8][2]) {
  const int tid  = threadIdx.x;
  const int w    = tid >> 6;
  const int lane = tid & 63;
  const int g    = (lane >> 4) & 3;
  const int c    = lane & 15;
  const int wm   = w >> 2;
  const int wn   = w & 3;

  auto stageA = [&](int t, int h) {
    const int buf = t & 1;
    #pragma unroll
    for (int i = 0; i < 2; ++i) {
      const int n  = i * 512 + w * 64 + lane;
      const int rh = n >> 3;
      const int j  = (n & 7) ^ (rh & 7);
      gload_lds16(Ag + (size_t)(m0 + h * 128 + rh) * 1024 + t * 64 + j * 8,
                  smem + AB_(buf, h) + (i * 512 + w * 64) * 8);
    }
  };
  auto stageB = [&](int t, int h) {
    const int buf = t & 1;
    const int n  = w * 64 + lane;
    const int rh = n >> 3;
    const int j  = (n & 7) ^ (rh & 7);
    gload_lds16(Bg + (size_t)(n0 + h * 64 + rh) * 1024 + t * 64 + j * 8,
                smem + BB_(buf, h) + (w * 64) * 8);
  };
  auto rdA = [&](int buf, int mi, int kk) -> short8 {
    const int rh = mi * 16 + c;
    const int cc = (kk * 4 + g) ^ (rh & 7);
    return *(const short8*)(smem + AB_(buf, wm) + rh * 64 + cc * 8);
  };
  auto rdB = [&](int buf, int ni, int kk) -> short8 {
    const int nr = wn * 32 + ni * 16 + c;
    const int h  = nr >> 6, rh = nr & 63;
    const int cc = (kk * 4 + g) ^ (rh & 7);
    return *(const short8*)(smem + BB_(buf, h) + rh * 64 + cc * 8);
  };

  stageA(0, 0); stageA(0, 1);
  stageB(0, 0); stageB(0, 1);
  stageA(1, 0); stageA(1, 1);
  VMC4();
  BAR();

  short8 Alo[4][2], Ahi[4][2], Br[2][2];
  #pragma unroll 2
  for (int t = 0; t < NT; ++t) {
    const int buf = t & 1;
    #pragma unroll
    for (int mi = 0; mi < 4; ++mi) {
      Alo[mi][0] = rdA(buf, mi, 0);
      Alo[mi][1] = rdA(buf, mi, 1);
    }
    #pragma unroll
    for (int ni = 0; ni < 2; ++ni) {
      Br[ni][0] = rdB(buf, ni, 0);
      Br[ni][1] = rdB(buf, ni, 1);
    }
    if (t + 1 < NT) stageB(t + 1, 0);
    LGKM0();
    __builtin_amdgcn_s_setprio(1);
    #pragma unroll
    for (int mi = 0; mi < 4; ++mi)
      #pragma unroll
      for (int ni = 0; ni < 2; ++ni)
        acc[mi][ni] = MFMA16(Alo[mi][0], Br[ni][0], acc[mi][ni]);
    __builtin_amdgcn_s_setprio(0);
    BAR();
    #pragma unroll
    for (int mi = 0; mi < 4; ++mi) {
      Ahi[mi][0] = rdA(buf, mi + 4, 0);
      Ahi[mi][1] = rdA(buf, mi + 4, 1);
    }
    if (t + 1 < NT) stageB(t + 1, 1);
    LGKM0();
    __builtin_amdgcn_s_setprio(1);
    #pragma unroll
    for (int mi = 0; mi < 4; ++mi)
      #pragma unroll
      for (int ni = 0; ni < 2; ++ni)
        acc[mi + 4][ni] = MFMA16(Ahi[mi][0], Br[ni][0], acc[mi + 4][ni]);
    __builtin_amdgcn_s_setprio(0);
    BAR();
    if (t + 2 < NT) { stageA(t + 2, 0); stageA(t + 2, 1); }
    __builtin_amdgcn_s_setprio(1);
    #pragma unroll
    for (int mi = 0; mi < 4; ++mi)
      #pragma unroll
      for (int ni = 0; ni < 2; ++ni)
        acc[mi][ni] = MFMA16(Alo[mi][1], Br[ni][1], acc[mi][ni]);
    #pragma unroll
    for (int mi = 0; mi < 4; ++mi)
      #pragma unroll
      for (int ni = 0; ni < 2; ++ni)
        acc[mi + 4][ni] = MFMA16(Ahi[mi][1], Br[ni][1], acc[mi + 4][ni]);
    __builtin_amdgcn_s_setprio(0);
    if (t + 1 < NT) {
      if (t + 2 < NT) { VMC4(); } else { VMC0(); }
    }
    BAR();
  }
}

// ---------------- GEMM1: QKV projection, scatter epilogue (V written transposed) ----------------
__global__ __launch_bounds__(512, 2) void gemm_qkv(const ushort* __restrict__ Xb,
                                                   const ushort* __restrict__ W,
                                                   ushort* __restrict__ Qb,
                                                   ushort* __restrict__ Kb,
                                                   ushort* __restrict__ Vtb) {
  __shared__ ushort smem[49152];   // 96 KB
  const int id  = blockIdx.x;                 // 768 blocks
  const int swz = (id & 7) * 96 + (id >> 3);  // XCD chunking (768%8==0)
  const int bm = swz / 24, bn = swz % 24;
  const int m0 = bm * 256, n0 = bn * 128;
  f32x4 acc[8][2] = {};
  gemm8_mainloop(Xb, W, m0, n0, smem, acc);

  const int tid = threadIdx.x;
  const int w = tid >> 6, lane = tid & 63;
  const int g = (lane >> 4) & 3, c = lane & 15;
  const int wm = w >> 2, wn = w & 3;
  #pragma unroll
  for (int mi = 0; mi < 8; ++mi) {
    #pragma unroll
    for (int ni = 0; ni < 2; ++ni) {
      const int n = n0 + wn * 32 + ni * 16 + c;
      const int part = n >> 10;
      const int h = (n >> 6) & 15;
      const int hd = n & 63;
      const int mbase = m0 + wm * 128 + mi * 16 + g * 4;
      const int b = mbase >> 12;
      const int lp0 = mbase & 4095;
      if (part == 0) {
        #pragma unroll
        for (int r = 0; r < 4; ++r)
          Qb[((size_t)((b << 4) + h) * 4096 + lp0 + r) * 64 + hd] =
              f2bf(acc[mi][ni][r] * QSCALE);
      } else if (part == 1) {
        #pragma unroll
        for (int r = 0; r < 4; ++r)
          Kb[((size_t)((b << 4) + h) * 4096 + lp0 + r) * 64 + hd] =
              f2bf(acc[mi][ni][r]);
      } else {
        uint2 pk;
        pk.x = cvt_pk_bf16(acc[mi][ni][0], acc[mi][ni][1]);
        pk.y = cvt_pk_bf16(acc[mi][ni][2], acc[mi][ni][3]);
        *(uint2*)&Vtb[((size_t)((b << 4) + h) * 64 + hd) * 4096 + lp0] = pk;
      }
    }
  }
}

// ---------------- GEMM2: output projection (128x128, 4 waves, 2 blocks/CU) ----------------
// BM=BN=128, BK=64, 256 thr = 4 waves (2M x 2N), wave tile 64x64, acc[4][4].
// LDS 64KB (A dbuf 2x16K + B dbuf 2x16K) -> 2 blocks/CU; grid 512 = 1 round.
// Single phase/K-tile: stage(t+1) -> read 16 frags -> 32 MFMA -> vmcnt(0) -> bar.
// Two co-resident blocks hide each other's barrier/vmcnt stalls (m97 recipe).
#define OA2_(buf) ((buf) * 8192)
#define OB2_(buf) (16384 + (buf) * 8192)

__global__ __launch_bounds__(256, 2) void gemm_out(const ushort* __restrict__ X2,
                                                   const ushort* __restrict__ W,
                                                   float* __restrict__ out) {
  __shared__ ushort smem[32768];   // 64 KB
  const int id  = blockIdx.x;                 // 512 blocks
  const int swz = (id & 7) * 64 + (id >> 3);  // XCD chunking (512%8==0)
  const int bm = swz >> 3, bn = swz & 7;
  const int m0 = bm * 128, n0 = bn * 128;
  const int tid = threadIdx.x;
  const int w = tid >> 6, lane = tid & 63;
  const int g = (lane >> 4) & 3, c = lane & 15;
  const int wm = w >> 1, wn = w & 1;
  const int rr = tid >> 3;                    // 0..31
  const int jj = (tid & 7) ^ (rr & 7);
  const int ca0 = g ^ (c & 7);
  const int ca1 = (4 + g) ^ (c & 7);

  auto stA = [&](int t) {                     // 4 chunks/thread (16KB tile)
    #pragma unroll
    for (int i = 0; i < 4; ++i)
      gload_lds16(X2 + (size_t)(m0 + i * 32 + rr) * 1024 + t * 64 + jj * 8,
                  smem + OA2_(t & 1) + (i * 256 + w * 64) * 8);
  };
  auto stB = [&](int t) {
    #pragma unroll
    for (int i = 0; i < 4; ++i)
      gload_lds16(W + (size_t)(n0 + i * 32 + rr) * 1024 + t * 64 + jj * 8,
                  smem + OB2_(t & 1) + (i * 256 + w * 64) * 8);
  };
  auto rdA = [&](int buf, int R, int cc) -> short8 {
    return *(const short8*)(smem + OA2_(buf) + R * 64 + cc * 8);
  };
  auto rdB = [&](int buf, int R, int cc) -> short8 {
    return *(const short8*)(smem + OB2_(buf) + R * 64 + cc * 8);
  };

  stA(0); stB(0);
  VMC0();
  BAR();

  f32x4 acc[4][4] = {};
  short8 Af[4][2], Bf[4][2];
  #pragma unroll 2
  for (int t = 0; t < NT; ++t) {
    const int buf = t & 1;
    if (t + 1 < NT) { stA(t + 1); stB(t + 1); }   // into buf^1
    #pragma unroll
    for (int mi = 0; mi < 4; ++mi) {
      const int R = wm * 64 + mi * 16 + c;
      Af[mi][0] = rdA(buf, R, ca0);
      Af[mi][1] = rdA(buf, R, ca1);
    }
    #pragma unroll
    for (int ni = 0; ni < 4; ++ni) {
      const int R = wn * 64 + ni * 16 + c;
      Bf[ni][0] = rdB(buf, R, ca0);
      Bf[ni][1] = rdB(buf, R, ca1);
    }
    LGKM0(); SCHED0();
    __builtin_amdgcn_s_setprio(1);
    #pragma unroll
    for (int mi = 0; mi < 4; ++mi)
      #pragma unroll
      for (int ni = 0; ni < 4; ++ni)
        acc[mi][ni] = MFMA16(Af[mi][0], Bf[ni][0], acc[mi][ni]);
    #pragma unroll
    for (int mi = 0; mi < 4; ++mi)
      #pragma unroll
      for (int ni = 0; ni < 4; ++ni)
        acc[mi][ni] = MFMA16(Af[mi][1], Bf[ni][1], acc[mi][ni]);
    __builtin_amdgcn_s_setprio(0);
    if (t + 1 < NT) VMC0();
    BAR();
  }

  #pragma unroll
  for (int mi = 0; mi < 4; ++mi) {
    #pragma unroll
    for (int ni = 0; ni < 4; ++ni) {
      const int n = n0 + wn * 64 + ni * 16 + c;
      #pragma unroll
      for (int r = 0; r < 4; ++r) {
        const int m = m0 + wm * 64 + mi * 16 + g * 4 + r;
        out[(size_t)m * 1024 + n] = acc[mi][ni][r];
      }
    }
  }
}

// ---------------- block-sparse flash attention (paired, static-max, T14 async stage) ----------------
// One block per (b,h,qb); 4 waves x 16 q-rows; pairs of kv-blocks (128 keys).
// T14: global->reg loads for pair p+1 issued right after pair p's ds_writes ->
// HBM latency hides under the full compute phase. Single LDS buffer (40KB,
// 4 blocks/CU). Static-max softmax (-8 folded into MFMA acc init).
__global__ __launch_bounds__(256, 4) void attn_kernel(const ushort* __restrict__ Qb,
                                                      const ushort* __restrict__ Kb,
                                                      const ushort* __restrict__ Vt,
                                                      const int* __restrict__ bidx,
                                                      const float* __restrict__ slopes,
                                                      ushort* __restrict__ X2) {
  __shared__ __align__(16) ushort Ks[8192];      // [128 keys][64 d], chunk-swizzled
  __shared__ __align__(16) ushort Vs[8192];      // [64 d][128 keys], chunk-swizzled
  __shared__ __align__(16) ushort Ps[4][16][64]; // per-wave P half, XOR-chunk swizzle

  const int phys = blockIdx.x;
  const int bid  = (phys & 7) * 256 + (phys >> 3);   // XCD swizzle
  const int qb = bid & 63;
  const int bh = bid >> 6;
  const int h  = bh & 15;
  const int b  = bh >> 4;
  const int tid = threadIdx.x;
  const int w = tid >> 6, lane = tid & 63;
  const int g = lane >> 4, c = lane & 15;
  const int i0 = w * 16;
  const float slope = slopes[h] * LOG2E;
  const int swz = c & 7;
  const int pkey = c & 14;

  const ushort* qptr = Qb + ((size_t)bh * 4096 + qb * 64 + i0 + c) * 64 + g * 8;
  const short8 qf0 = *(const short8*)qptr;
  const short8 qf1 = *(const short8*)(qptr + 32);

  const int* bl = bidx + qb * MAXB;

  uint4 kreg[4], vreg[4];
  auto issue = [&](int b1, int b2) {
    #pragma unroll
    for (int j2 = 0; j2 < 4; ++j2) {
      const int n = j2 * 256 + tid;
      const int row = n >> 3;
      const int kbk = (row >> 6) ? b2 : b1;
      const int sc = ((n & 7) ^ (row & 7)) * 8;
      kreg[j2] = *(const uint4*)(Kb + ((size_t)bh * 4096 + kbk * 64 + (row & 63)) * 64 + sc);
    }
    #pragma unroll
    for (int j2 = 0; j2 < 4; ++j2) {
      const int n = j2 * 256 + tid;
      const int d = n >> 4;
      const int cr = n & 15;
      const int kbk = (cr >> 3) ? b2 : b1;
      const int sc = ((cr & 7) ^ (d & 7)) * 8;
      vreg[j2] = *(const uint4*)(Vt + ((size_t)bh * 64 + d) * 4096 + kbk * 64 + sc);
    }
  };

  int kb1 = bl[0];
  int kb2r = bl[1];
  bool pad = (kb2r < 0);
  int kb2 = pad ? kb1 : kb2r;
  issue(kb1, kb2);

  f32x4 accO[4] = {};
  float lrun = 0.f;
  const int qi = qb * 64 + i0 + c;
  const f32x4 minit = {-8.f, -8.f, -8.f, -8.f};

  #pragma unroll 1
  for (int p = 0; p < 6; ++p) {
    // write current pair's regs to LDS (compiler emits the vmcnt wait; the
    // loads had the entire previous compute phase to land -> ~0 wait)
    #pragma unroll
    for (int j2 = 0; j2 < 4; ++j2)
      *(uint4*)&Ks[(j2 * 256 + tid) * 8] = kreg[j2];
    #pragma unroll
    for (int j2 = 0; j2 < 4; ++j2)
      *(uint4*)&Vs[(j2 * 256 + tid) * 8] = vreg[j2];

    const int ckb1 = kb1, ckb2 = kb2;
    const bool cpad = pad;
    // next-pair scalars + EARLY issue (overlaps all compute below)
    const int p2 = 2 * p + 2;
    const int nkb1  = (p2 < MAXB) ? bl[p2] : -1;
    const int nkb2r = (p2 + 1 < MAXB) ? bl[p2 + 1] : -1;
    if (nkb1 >= 0) {
      pad = (nkb2r < 0);
      kb1 = nkb1;
      kb2 = pad ? nkb1 : nkb2r;
      issue(kb1, kb2);
    }
    SCHED0();               // pin load issue above compute
    LGKM0();                // own ds_writes complete
    BAR();                  // all waves' writes visible

    // S^T = K * Q^T over 128 keys, accumulator pre-loaded with -8
    f32x4 s[8];
    #pragma unroll
    for (int bi = 0; bi < 2; ++bi)
      #pragma unroll
      for (int ni = 0; ni < 4; ++ni) {
        f32x4 z = minit;
        const ushort* kr = Ks + (bi * 64 + ni * 16 + c) * 64;
        z = MFMA16(*(const short8*)(kr + (g ^ swz) * 8), qf0, z);
        z = MFMA16(*(const short8*)(kr + ((4 + g) ^ swz) * 8), qf1, z);
        s[bi * 4 + ni] = z;
      }

    // ALiBi + exp2 (static max folded); lane-local l accumulation
    #pragma unroll
    for (int bi = 0; bi < 2; ++bi) {
      const int kbb = bi ? ckb2 : ckb1;
      const int ib0 = qi - kbb * 64 - g * 4;
      #pragma unroll
      for (int ni = 0; ni < 4; ++ni) {
        const float base = (float)(ib0 - ni * 16);
        #pragma unroll
        for (int r = 0; r < 4; ++r)
          s[bi * 4 + ni][r] = fmaf(-slope, fabsf(base - (float)r), s[bi * 4 + ni][r]);
      }
    }
    if (cpad) {
      #pragma unroll
      for (int k = 4; k < 8; ++k)
        #pragma unroll
        for (int r = 0; r < 4; ++r)
          s[k][r] = -1e9f;
    }
    #pragma unroll
    for (int k = 0; k < 8; ++k)
      #pragma unroll
      for (int r = 0; r < 4; ++r) {
        const float pv = __builtin_amdgcn_exp2f(s[k][r]);
        s[k][r] = pv;
        lrun += pv;
      }

    // ---- PV half 1 (keys 0..63) ----
    #pragma unroll
    for (int ni = 0; ni < 4; ++ni) {
      uint2 pk;
      pk.x = cvt_pk_bf16(s[ni][0], s[ni][1]);
      pk.y = cvt_pk_bf16(s[ni][2], s[ni][3]);
      *(uint2*)&Ps[w][c][((ni * 4 + g) ^ pkey) * 4] = pk;
    }
    asm volatile("s_waitcnt lgkmcnt(0)" ::: "memory");
    SCHED0();
    {
      const short8 pf0 = *(const short8*)&Ps[w][c][((2 * g) ^ pkey) * 4];
      const short8 pf1 = *(const short8*)&Ps[w][c][((8 + 2 * g) ^ pkey) * 4];
      #pragma unroll
      for (int di = 0; di < 4; ++di) {
        const ushort* vr = Vs + (di * 16 + c) * 128;
        accO[di] = MFMA16(*(const short8*)(vr + (g ^ swz) * 8), pf0, accO[di]);
        accO[di] = MFMA16(*(const short8*)(vr + ((4 + g) ^ swz) * 8), pf1, accO[di]);
      }
    }
    // ---- PV half 2 (keys 64..127), reuse Ps buffer ----
    SCHED0();
    #pragma unroll
    for (int ni = 0; ni < 4; ++ni) {
      uint2 pk;
      pk.x = cvt_pk_bf16(s[4 + ni][0], s[4 + ni][1]);
      pk.y = cvt_pk_bf16(s[4 + ni][2], s[4 + ni][3]);
      *(uint2*)&Ps[w][c][((ni * 4 + g) ^ pkey) * 4] = pk;
    }
    asm volatile("s_waitcnt lgkmcnt(0)" ::: "memory");
    SCHED0();
    {
      const short8 pf2 = *(const short8*)&Ps[w][c][((2 * g) ^ pkey) * 4];
      const short8 pf3 = *(const short8*)&Ps[w][c][((8 + 2 * g) ^ pkey) * 4];
      #pragma unroll
      for (int di = 0; di < 4; ++di) {
        const ushort* vr = Vs + (di * 16 + c) * 128;
        accO[di] = MFMA16(*(const short8*)(vr + (8 | (g ^ swz)) * 8), pf2, accO[di]);
        accO[di] = MFMA16(*(const short8*)(vr + (8 | ((4 + g) ^ swz)) * 8), pf3, accO[di]);
      }
    }
    BAR();   // all waves done reading Ks/Vs -> next iteration may overwrite
    if (nkb1 < 0) break;
  }

  // epilogue: row denominator, then O/l
  float l = lrun;
  l += __shfl_xor(l, 16);
  l += __shfl_xor(l, 32);
  const float rl = __builtin_amdgcn_rcpf(l);
  const size_t orow = (size_t)b * 4096 + qb * 64 + i0 + c;
  #pragma unroll
  for (int di = 0; di < 4; ++di) {
    uint2 pk;
    pk.x = cvt_pk_bf16(accO[di][0] * rl, accO[di][1] * rl);
    pk.y = cvt_pk_bf16(accO[di][2] * rl, accO[di][3] * rl);
    *(uint2*)&X2[orow * 1024 + h * 64 + di * 16 + g * 4] = pk;
  }
}

// ---------------- launch ----------------
extern "C" void kernel_launch(void* const* d_in, const int* in_sizes, int n_in,
                              void* d_out, int out_size, void* d_ws, size_t ws_size,
                              hipStream_t stream) {
  (void)in_sizes; (void)n_in; (void)out_size; (void)ws_size;
  const float* hs     = (const float*)d_in[0];
  const float* Wq     = (const float*)d_in[1];
  const float* Wk     = (const float*)d_in[2];
  const float* Wv     = (const float*)d_in[3];
  const float* Wo     = (const float*)d_in[4];
  const float* slopes = (const float*)d_in[5];
  const int*   bidx   = (const int*)d_in[6];
  float* out = (float*)d_out;

  char* ws = (char*)d_ws;
  ushort* Xb   = (ushort*)(ws + 0);             // 16 MB (dead after gemm_qkv; reused as X2)
  ushort* Wqkv = (ushort*)(ws + 16777216);      //  6 MB
  ushort* Wob  = (ushort*)(ws + 23068672);      //  2 MB
  ushort* Qb   = (ushort*)(ws + 25165824);      // 16 MB
  ushort* Kb   = (ushort*)(ws + 41943040);      // 16 MB
  ushort* Vtb  = (ushort*)(ws + 58720256);      // 16 MB ([B,H,64,L], written by gemm_qkv)
  ushort* X2   = Xb;

  cvt_kernel<<<8192, 256, 0, stream>>>(hs, Xb, 2097152);
  cvt4_kernel<<<4096, 256, 0, stream>>>(Wq, Wk, Wv, Wo, Wqkv, Wob);

  gemm_qkv<<<768, 512, 0, stream>>>(Xb, Wqkv, Qb, Kb, Vtb);
  attn_kernel<<<2048, 256, 0, stream>>>(Qb, Kb, Vtb, bidx, slopes, X2);
  gemm_out<<<512, 256, 0, stream>>>(X2, Wob, out);
}

// Round 10
// 153.456 us; speedup vs baseline: 1.8776x; 1.8776x over previous
//
#include <hip/hip_runtime.h>
#include <cstdint>
#include <cstddef>

// ---------------------------------------------------------------
// SparseAttention: B=2 L=4096 D=1024 H=16 HD=64 BS=64 NB=64 MAXB=11
// ---------------------------------------------------------------

#define MAXB 11
#define NT   16    // K-tiles: K=1024 / BK=64

typedef __attribute__((ext_vector_type(8))) short short8;
typedef __attribute__((ext_vector_type(4))) float f32x4;

#define MFMA16(a, b, c) __builtin_amdgcn_mfma_f32_16x16x32_bf16((a), (b), (c), 0, 0, 0)

#define QSCALE 0.18033688011112042f   // 0.125 * log2(e)
#define LOG2E  1.44269504089f

#define BAR()   asm volatile("s_barrier" ::: "memory")
#define LGKM0() asm volatile("s_waitcnt lgkmcnt(0)" ::: "memory")
#define SCHED0() __builtin_amdgcn_sched_barrier(0)
#define VMC0()  asm volatile("s_waitcnt vmcnt(0)" ::: "memory")

__device__ __forceinline__ ushort f2bf(float f) {
  uint32_t u = __float_as_uint(f);
  u += 0x7FFFu + ((u >> 16) & 1u);   // RNE
  return (ushort)(u >> 16);
}

__device__ __forceinline__ uint32_t cvt_pk_bf16(float lo, float hi) {
  uint32_t r;
  asm("v_cvt_pk_bf16_f32 %0, %1, %2" : "=v"(r) : "v"(lo), "v"(hi));
  return r;
}

__device__ __forceinline__ void gload_lds16(const ushort* g, ushort* l) {
  __builtin_amdgcn_global_load_lds((const __attribute__((address_space(1))) void*)g,
                                   (__attribute__((address_space(3))) void*)l, 16, 0, 0);
}

// ---------------- f32 -> bf16 conversion ----------------
__global__ __launch_bounds__(256) void cvt_kernel(const float* __restrict__ src,
                                                  ushort* __restrict__ dst, int n4) {
  int i = blockIdx.x * 256 + threadIdx.x;
  if (i >= n4) return;
  const float4 v = reinterpret_cast<const float4*>(src)[i];
  ushort4 o;
  o.x = f2bf(v.x); o.y = f2bf(v.y); o.z = f2bf(v.z); o.w = f2bf(v.w);
  reinterpret_cast<ushort4*>(dst)[i] = o;
}

// fused weight conversion: Wq,Wk,Wv -> Wqkv (contig), Wo -> Wob
__global__ __launch_bounds__(256) void cvt4_kernel(const float* __restrict__ wq,
                                                   const float* __restrict__ wk,
                                                   const float* __restrict__ wv,
                                                   const float* __restrict__ wo,
                                                   ushort* __restrict__ wqkv,
                                                   ushort* __restrict__ wob) {
  int i = blockIdx.x * 256 + threadIdx.x;      // 0 .. 4*262144-1
  const int part = i >> 18;
  const int j = i & 262143;
  const float* src = (part == 0) ? wq : (part == 1) ? wk : (part == 2) ? wv : wo;
  const float4 v = reinterpret_cast<const float4*>(src)[j];
  ushort4 o;
  o.x = f2bf(v.x); o.y = f2bf(v.y); o.z = f2bf(v.z); o.w = f2bf(v.w);
  if (part < 3) reinterpret_cast<ushort4*>(wqkv)[part * 262144 + j] = o;
  else          reinterpret_cast<ushort4*>(wob)[j] = o;
}

// ---------------- 128x128 / 4-wave / 2-blocks-per-CU GEMM mainloop ----------------
// BM=BN=128, BK=64, 256 thr = 4 waves (2M x 2N), wave tile 64x64, acc[4][4].
// LDS 64KB (A dbuf 2x16K + B dbuf 2x16K) -> 2 blocks/CU. Single phase/K-tile:
// stage(t+1) -> read 16 frags -> 32 MFMA -> vmcnt(0) -> bar. Two co-resident
// blocks hide each other's stalls (m97 recipe; measured ~12us on gemm_out r9).
#define GA_(buf) ((buf) * 8192)
#define GB_(buf) (16384 + (buf) * 8192)

__device__ __forceinline__ void gemm4_mainloop(const ushort* __restrict__ Ag,
                                               const ushort* __restrict__ Bg,
                                               int m0, int n0,
                                               ushort* smem, f32x4 acc[4][4]) {
  const int tid = threadIdx.x;
  const int w = tid >> 6, lane = tid & 63;
  const int g = (lane >> 4) & 3, c = lane & 15;
  const int wm = w >> 1, wn = w & 1;
  const int rr = tid >> 3;                    // 0..31
  const int jj = (tid & 7) ^ (rr & 7);
  const int ca0 = g ^ (c & 7);
  const int ca1 = (4 + g) ^ (c & 7);

  auto stA = [&](int t) {                     // 4 chunks/thread (16KB tile)
    #pragma unroll
    for (int i = 0; i < 4; ++i)
      gload_lds16(Ag + (size_t)(m0 + i * 32 + rr) * 1024 + t * 64 + jj * 8,
                  smem + GA_(t & 1) + (i * 256 + w * 64) * 8);
  };
  auto stB = [&](int t) {
    #pragma unroll
    for (int i = 0; i < 4; ++i)
      gload_lds16(Bg + (size_t)(n0 + i * 32 + rr) * 1024 + t * 64 + jj * 8,
                  smem + GB_(t & 1) + (i * 256 + w * 64) * 8);
  };
  auto rdA = [&](int buf, int R, int cc) -> short8 {
    return *(const short8*)(smem + GA_(buf) + R * 64 + cc * 8);
  };
  auto rdB = [&](int buf, int R, int cc) -> short8 {
    return *(const short8*)(smem + GB_(buf) + R * 64 + cc * 8);
  };

  stA(0); stB(0);
  VMC0();
  BAR();

  short8 Af[4][2], Bf[4][2];
  #pragma unroll 2
  for (int t = 0; t < NT; ++t) {
    const int buf = t & 1;
    if (t + 1 < NT) { stA(t + 1); stB(t + 1); }   // into buf^1
    #pragma unroll
    for (int mi = 0; mi < 4; ++mi) {
      const int R = wm * 64 + mi * 16 + c;
      Af[mi][0] = rdA(buf, R, ca0);
      Af[mi][1] = rdA(buf, R, ca1);
    }
    #pragma unroll
    for (int ni = 0; ni < 4; ++ni) {
      const int R = wn * 64 + ni * 16 + c;
      Bf[ni][0] = rdB(buf, R, ca0);
      Bf[ni][1] = rdB(buf, R, ca1);
    }
    LGKM0(); SCHED0();
    __builtin_amdgcn_s_setprio(1);
    #pragma unroll
    for (int mi = 0; mi < 4; ++mi)
      #pragma unroll
      for (int ni = 0; ni < 4; ++ni)
        acc[mi][ni] = MFMA16(Af[mi][0], Bf[ni][0], acc[mi][ni]);
    #pragma unroll
    for (int mi = 0; mi < 4; ++mi)
      #pragma unroll
      for (int ni = 0; ni < 4; ++ni)
        acc[mi][ni] = MFMA16(Af[mi][1], Bf[ni][1], acc[mi][ni]);
    __builtin_amdgcn_s_setprio(0);
    if (t + 1 < NT) VMC0();
    BAR();
  }
}

// ---------------- GEMM1: QKV projection, 128x128, scatter epilogue ----------------
// Grid 1536 = 3 full 2-blocks/CU rounds. XCD chunk: per XCD bm-major -> A-slice
// 2MB L2-resident, B 6MB in L2+L3.
__global__ __launch_bounds__(256, 2) void gemm_qkv(const ushort* __restrict__ Xb,
                                                   const ushort* __restrict__ W,
                                                   ushort* __restrict__ Qb,
                                                   ushort* __restrict__ Kb,
                                                   ushort* __restrict__ Vtb) {
  __shared__ ushort smem[32768];   // 64 KB
  const int id  = blockIdx.x;                   // 1536 blocks
  const int swz = (id & 7) * 192 + (id >> 3);   // XCD chunking (1536%8==0)
  const int bm = swz / 24, bn = swz % 24;
  const int m0 = bm * 128, n0 = bn * 128;
  f32x4 acc[4][4] = {};
  gemm4_mainloop(Xb, W, m0, n0, smem, acc);

  const int tid = threadIdx.x;
  const int w = tid >> 6, lane = tid & 63;
  const int g = (lane >> 4) & 3, c = lane & 15;
  const int wm = w >> 1, wn = w & 1;
  #pragma unroll
  for (int mi = 0; mi < 4; ++mi) {
    #pragma unroll
    for (int ni = 0; ni < 4; ++ni) {
      const int n = n0 + wn * 64 + ni * 16 + c;
      const int part = n >> 10;
      const int h = (n >> 6) & 15;
      const int hd = n & 63;
      const int mbase = m0 + wm * 64 + mi * 16 + g * 4;
      const int b = mbase >> 12;            // 4-row group never crosses b
      const int lp0 = mbase & 4095;
      if (part == 0) {
        #pragma unroll
        for (int r = 0; r < 4; ++r)
          Qb[((size_t)((b << 4) + h) * 4096 + lp0 + r) * 64 + hd] =
              f2bf(acc[mi][ni][r] * QSCALE);
      } else if (part == 1) {
        #pragma unroll
        for (int r = 0; r < 4; ++r)
          Kb[((size_t)((b << 4) + h) * 4096 + lp0 + r) * 64 + hd] =
              f2bf(acc[mi][ni][r]);
      } else {
        uint2 pk;
        pk.x = cvt_pk_bf16(acc[mi][ni][0], acc[mi][ni][1]);
        pk.y = cvt_pk_bf16(acc[mi][ni][2], acc[mi][ni][3]);
        *(uint2*)&Vtb[((size_t)((b << 4) + h) * 64 + hd) * 4096 + lp0] = pk;
      }
    }
  }
}

// ---------------- GEMM2: output projection, 128x128, f32 store (r9, measured ~12us) ----------------
__global__ __launch_bounds__(256, 2) void gemm_out(const ushort* __restrict__ X2,
                                                   const ushort* __restrict__ W,
                                                   float* __restrict__ out) {
  __shared__ ushort smem[32768];   // 64 KB
  const int id  = blockIdx.x;                 // 512 blocks
  const int swz = (id & 7) * 64 + (id >> 3);  // XCD chunking (512%8==0)
  const int bm = swz >> 3, bn = swz & 7;
  const int m0 = bm * 128, n0 = bn * 128;
  f32x4 acc[4][4] = {};
  gemm4_mainloop(X2, W, m0, n0, smem, acc);

  const int tid = threadIdx.x;
  const int w = tid >> 6, lane = tid & 63;
  const int g = (lane >> 4) & 3, c = lane & 15;
  const int wm = w >> 1, wn = w & 1;
  #pragma unroll
  for (int mi = 0; mi < 4; ++mi) {
    #pragma unroll
    for (int ni = 0; ni < 4; ++ni) {
      const int n = n0 + wn * 64 + ni * 16 + c;
      #pragma unroll
      for (int r = 0; r < 4; ++r) {
        const int m = m0 + wm * 64 + mi * 16 + g * 4 + r;
        out[(size_t)m * 1024 + n] = acc[mi][ni][r];
      }
    }
  }
}

// ---------------- block-sparse flash attention (round-8 version: paired blocks,
// static-max softmax, gload_lds staging) ----------------
__global__ __launch_bounds__(256, 4) void attn_kernel(const ushort* __restrict__ Qb,
                                                      const ushort* __restrict__ Kb,
                                                      const ushort* __restrict__ Vt,
                                                      const int* __restrict__ bidx,
                                                      const float* __restrict__ slopes,
                                                      ushort* __restrict__ X2) {
  __shared__ __align__(16) ushort Ks[8192];      // [128 keys][64 d], chunk-swizzled
  __shared__ __align__(16) ushort Vs[8192];      // [64 d][128 keys], chunk-swizzled
  __shared__ __align__(16) ushort Ps[4][16][64]; // per-wave P half, XOR-chunk swizzle

  const int phys = blockIdx.x;
  const int bid  = (phys & 7) * 256 + (phys >> 3);   // XCD swizzle
  const int qb = bid & 63;
  const int bh = bid >> 6;
  const int h  = bh & 15;
  const int b  = bh >> 4;
  const int tid = threadIdx.x;
  const int w = tid >> 6, lane = tid & 63;
  const int g = lane >> 4, c = lane & 15;
  const int i0 = w * 16;
  const float slope = slopes[h] * LOG2E;
  const int swz = c & 7;
  const int pkey = c & 14;                           // Ps XOR key

  const ushort* qptr = Qb + ((size_t)bh * 4096 + qb * 64 + i0 + c) * 64 + g * 8;
  const short8 qf0 = *(const short8*)qptr;
  const short8 qf1 = *(const short8*)(qptr + 32);

  // stage one PAIR (kb1: keys 0..63, kb2: keys 64..127). 8 loads/thread.
  auto stage = [&](int kb1, int kb2) {
    #pragma unroll
    for (int jj = 0; jj < 4; ++jj) {
      const int n = jj * 256 + tid;                  // K chunk 0..1023
      const int row = n >> 3;                        // key 0..127
      const int kbk = (row >> 6) ? kb2 : kb1;
      const int sc = ((n & 7) ^ (row & 7)) * 8;
      gload_lds16(Kb + ((size_t)bh * 4096 + kbk * 64 + (row & 63)) * 64 + sc,
                  Ks + (jj * 256 + (w << 6)) * 8);
    }
    #pragma unroll
    for (int jj = 0; jj < 4; ++jj) {
      const int n = jj * 256 + tid;                  // V chunk 0..1023
      const int d = n >> 4;                          // d row 0..63
      const int cr = n & 15;                         // 16B chunk within row
      const int kbk = (cr >> 3) ? kb2 : kb1;
      const int sc = ((cr & 7) ^ (d & 7)) * 8;
      gload_lds16(Vt + ((size_t)bh * 64 + d) * 4096 + kbk * 64 + sc,
                  Vs + (jj * 256 + (w << 6)) * 8);
    }
  };

  f32x4 accO[4] = {};
  float lrun = 0.f;                    // lane-local partial denominator
  const int qi = qb * 64 + i0 + c;
  const f32x4 minit = {-8.f, -8.f, -8.f, -8.f};   // static-max fold

  #pragma unroll 1
  for (int p = 0; p < (MAXB + 1) / 2; ++p) {
    const int kb1 = bidx[qb * MAXB + 2 * p];                    // uniform
    if (kb1 < 0) break;                                         // -1s only at tail
    const int kb2r = (2 * p + 1 < MAXB) ? bidx[qb * MAXB + 2 * p + 1] : -1;
    const bool pad = (kb2r < 0);
    const int kb2 = pad ? kb1 : kb2r;

    stage(kb1, kb2);
    VMC0();
    BAR();

    // S^T = K * Q^T over 128 keys, accumulator pre-loaded with -8
    f32x4 s[8];
    #pragma unroll
    for (int bi = 0; bi < 2; ++bi)
      #pragma unroll
      for (int ni = 0; ni < 4; ++ni) {
        f32x4 z = minit;
        const ushort* kr = Ks + (bi * 64 + ni * 16 + c) * 64;
        z = MFMA16(*(const short8*)(kr + (g ^ swz) * 8), qf0, z);
        z = MFMA16(*(const short8*)(kr + ((4 + g) ^ swz) * 8), qf1, z);
        s[bi * 4 + ni] = z;
      }

    // ALiBi + exp2 (static max already folded); lane-local l accumulation
    #pragma unroll
    for (int bi = 0; bi < 2; ++bi) {
      const int kbb = bi ? kb2 : kb1;
      const int ib0 = qi - kbb * 64 - g * 4;
      #pragma unroll
      for (int ni = 0; ni < 4; ++ni) {
        const float base = (float)(ib0 - ni * 16);
        #pragma unroll
        for (int r = 0; r < 4; ++r)
          s[bi * 4 + ni][r] = fmaf(-slope, fabsf(base - (float)r), s[bi * 4 + ni][r]);
      }
    }
    if (pad) {
      #pragma unroll
      for (int k = 4; k < 8; ++k)
        #pragma unroll
        for (int r = 0; r < 4; ++r)
          s[k][r] = -1e9f;
    }
    #pragma unroll
    for (int k = 0; k < 8; ++k)
      #pragma unroll
      for (int r = 0; r < 4; ++r) {
        const float pv = __builtin_amdgcn_exp2f(s[k][r]);
        s[k][r] = pv;
        lrun += pv;
      }

    // ---- PV half 1 (keys 0..63) ----
    #pragma unroll
    for (int ni = 0; ni < 4; ++ni) {
      uint2 pk;
      pk.x = cvt_pk_bf16(s[ni][0], s[ni][1]);
      pk.y = cvt_pk_bf16(s[ni][2], s[ni][3]);
      *(uint2*)&Ps[w][c][((ni * 4 + g) ^ pkey) * 4] = pk;
    }
    asm volatile("s_waitcnt lgkmcnt(0)" ::: "memory");
    SCHED0();
    {
      const short8 pf0 = *(const short8*)&Ps[w][c][((2 * g) ^ pkey) * 4];
      const short8 pf1 = *(const short8*)&Ps[w][c][((8 + 2 * g) ^ pkey) * 4];
      #pragma unroll
      for (int di = 0; di < 4; ++di) {
        const ushort* vr = Vs + (di * 16 + c) * 128;
        accO[di] = MFMA16(*(const short8*)(vr + (g ^ swz) * 8), pf0, accO[di]);
        accO[di] = MFMA16(*(const short8*)(vr + ((4 + g) ^ swz) * 8), pf1, accO[di]);
      }
    }
    // ---- PV half 2 (keys 64..127), reuse Ps buffer ----
    SCHED0();
    #pragma unroll
    for (int ni = 0; ni < 4; ++ni) {
      uint2 pk;
      pk.x = cvt_pk_bf16(s[4 + ni][0], s[4 + ni][1]);
      pk.y = cvt_pk_bf16(s[4 + ni][2], s[4 + ni][3]);
      *(uint2*)&Ps[w][c][((ni * 4 + g) ^ pkey) * 4] = pk;
    }
    asm volatile("s_waitcnt lgkmcnt(0)" ::: "memory");
    SCHED0();
    {
      const short8 pf2 = *(const short8*)&Ps[w][c][((2 * g) ^ pkey) * 4];
      const short8 pf3 = *(const short8*)&Ps[w][c][((8 + 2 * g) ^ pkey) * 4];
      #pragma unroll
      for (int di = 0; di < 4; ++di) {
        const ushort* vr = Vs + (di * 16 + c) * 128;
        accO[di] = MFMA16(*(const short8*)(vr + (8 | (g ^ swz)) * 8), pf2, accO[di]);
        accO[di] = MFMA16(*(const short8*)(vr + (8 | ((4 + g) ^ swz)) * 8), pf3, accO[di]);
      }
    }
    BAR();   // all waves done reading Ks/Vs -> next stage may overwrite
  }

  // epilogue: row denominator = lane partial + partners (g-dim), then O/l
  float l = lrun;
  l += __shfl_xor(l, 16);
  l += __shfl_xor(l, 32);
  const float rl = __builtin_amdgcn_rcpf(l);
  const size_t orow = (size_t)b * 4096 + qb * 64 + i0 + c;
  #pragma unroll
  for (int di = 0; di < 4; ++di) {
    uint2 pk;
    pk.x = cvt_pk_bf16(accO[di][0] * rl, accO[di][1] * rl);
    pk.y = cvt_pk_bf16(accO[di][2] * rl, accO[di][3] * rl);
    *(uint2*)&X2[orow * 1024 + h * 64 + di * 16 + g * 4] = pk;
  }
}

// ---------------- launch ----------------
extern "C" void kernel_launch(void* const* d_in, const int* in_sizes, int n_in,
                              void* d_out, int out_size, void* d_ws, size_t ws_size,
                              hipStream_t stream) {
  (void)in_sizes; (void)n_in; (void)out_size; (void)ws_size;
  const float* hs     = (const float*)d_in[0];
  const float* Wq     = (const float*)d_in[1];
  const float* Wk     = (const float*)d_in[2];
  const float* Wv     = (const float*)d_in[3];
  const float* Wo     = (const float*)d_in[4];
  const float* slopes = (const float*)d_in[5];
  const int*   bidx   = (const int*)d_in[6];
  float* out = (float*)d_out;

  char* ws = (char*)d_ws;
  ushort* Xb   = (ushort*)(ws + 0);             // 16 MB (dead after gemm_qkv; reused as X2)
  ushort* Wqkv = (ushort*)(ws + 16777216);      //  6 MB
  ushort* Wob  = (ushort*)(ws + 23068672);      //  2 MB
  ushort* Qb   = (ushort*)(ws + 25165824);      // 16 MB
  ushort* Kb   = (ushort*)(ws + 41943040);      // 16 MB
  ushort* Vtb  = (ushort*)(ws + 58720256);      // 16 MB ([B,H,64,L], written by gemm_qkv)
  ushort* X2   = Xb;

  cvt_kernel<<<8192, 256, 0, stream>>>(hs, Xb, 2097152);
  cvt4_kernel<<<4096, 256, 0, stream>>>(Wq, Wk, Wv, Wo, Wqkv, Wob);

  gemm_qkv<<<1536, 256, 0, stream>>>(Xb, Wqkv, Qb, Kb, Vtb);
  attn_kernel<<<2048, 256, 0, stream>>>(Qb, Kb, Vtb, bidx, slopes, X2);
  gemm_out<<<512, 256, 0, stream>>>(X2, Wob, out);
}